// Round 3
// baseline (862.119 us; speedup 1.0000x reference)
//
#include <hip/hip_runtime.h>
#include <math.h>

#define BN 4
#define CN 64
#define HN 64
#define WN 256
#define ON 64
#define NOC 18
#define PN 9
#define HO 31
#define WO 127

__device__ __forceinline__ float trianglewave(float x) {
    const float PI_F = 3.14159274101257324f;   // float(np.pi)
    float n = floorf(x / PI_F + 0.5f);
    float m = fmodf(n, 2.0f);
    if (m < 0.0f) m += 2.0f;
    float sgn = 1.0f - 2.0f * m;
    return (x - PI_F * n) * sgn;
}

__device__ __forceinline__ float prak_f(float x) {
    const float PI_HALF = 1.57079637050628662f; // float(np.pi/2)
    return trianglewave(x) + trianglewave(x + PI_HALF);
}

// Transpose weights:
//  wA[c][k][oc]  (c*9+k)*18+oc   <- offset_w[((oc*64+c)*9+k)]
//  wB[p][c][o]   (p*64+c)*64+o   <- weight[(o*64+c)*9+p]
__global__ void prep_kernel(const float* __restrict__ offw,
                            const float* __restrict__ wgt,
                            float* __restrict__ wA,
                            float* __restrict__ wB) {
    int t = blockIdx.x * blockDim.x + threadIdx.x;
    if (t < CN * 9 * NOC) {
        int oc = t % NOC;
        int k  = (t / NOC) % 9;
        int c  = t / (NOC * 9);
        wA[t] = offw[(oc * CN + c) * 9 + k];
    }
    if (t < PN * CN * ON) {
        int o = t % ON;
        int c = (t / ON) % CN;
        int p = t / (ON * CN);
        wB[t] = wgt[(o * CN + c) * 9 + p];
    }
}

// block (64 w-lanes, 4 c-groups); grid 1024 with XCD-chunked swizzle
__global__ __launch_bounds__(256) void offsets_kernel(const float* __restrict__ x,
                                                      const float* __restrict__ wA,
                                                      const float* __restrict__ offb,
                                                      float* __restrict__ offs) {
    __shared__ float red[4][64][19];
    int bid = blockIdx.x;
    int logical = ((bid & 7) << 7) + (bid >> 3);  // contiguous 128-chunk per XCD
    int b = logical >> 8;
    int h = (logical >> 2) & 63;
    int wblk = logical & 3;
    int wlane = threadIdx.x;
    int cg = threadIdx.y;
    int w = (wblk << 6) + wlane;

    float acc[NOC];
#pragma unroll
    for (int i = 0; i < NOC; i++) acc[i] = 0.0f;

    const float* xc = x + ((size_t)b * CN + cg * 16) * HN * WN;
    for (int c = 0; c < 16; c++, xc += HN * WN) {
        const float* wa = wA + ((cg * 16 + c) * 9) * NOC;
#pragma unroll
        for (int k = 0; k < 9; k++) {
            int iy = h + k / 3 - 1;
            int ix = w + k % 3 - 1;
            float xv = (iy >= 0 && iy < HN && ix >= 0 && ix < WN) ? xc[iy * WN + ix] : 0.0f;
#pragma unroll
            for (int oc = 0; oc < NOC; oc++) acc[oc] += xv * wa[k * NOC + oc];
        }
    }
#pragma unroll
    for (int oc = 0; oc < NOC; oc++) red[cg][wlane][oc] = acc[oc];
    __syncthreads();
    if (cg == 0) {
#pragma unroll
        for (int oc = 0; oc < NOC; oc++) {
            float t = red[0][wlane][oc] + red[1][wlane][oc] +
                      red[2][wlane][oc] + red[3][wlane][oc] + offb[oc];
            offs[((b * NOC + oc) * HN + h) * WN + w] = t;
        }
    }
}

// Deformable conv, c-split across blocks for occupancy.
// block: (64 w, 2 og, 2 cg); grid 2048 XCD-swizzled
// logical = [b][h][wblk][chalf]; block covers 32 channels (chalf), 16 per cg.
__global__ __launch_bounds__(256, 8) void deform_kernel(const float* __restrict__ x,
                                                        const float* __restrict__ offs,
                                                        const float* __restrict__ mask,
                                                        const float* __restrict__ wB,
                                                        float* __restrict__ ypart) {
    __shared__ float red[64 * 65];      // cg=1 acc spill, padded stride 65

    int bid = blockIdx.x;
    int logical = ((bid & 7) << 8) + (bid >> 3);   // 8 XCDs x 256-chunk
    int chalf = logical & 1;
    int wblk = (logical >> 1) & 3;
    int h = (logical >> 3) & 63;
    int b = logical >> 9;

    int wlane = threadIdx.x;            // 0..63
    int og = threadIdx.y;               // 0..1
    int cg = threadIdx.z;               // 0..1
    int w = (wblk << 6) + wlane;
    int obase = og << 5;
    int cbase = (chalf << 5) + (cg << 4);

    float acc[32];
#pragma unroll
    for (int i = 0; i < 32; i++) acc[i] = 0.0f;

    const float* xb = x + ((size_t)b * CN + cbase) * HN * WN;

    for (int p = 0; p < PN; p++) {
        float offy = offs[((b * NOC + 2 * p) * HN + h) * WN + w];
        float offx = offs[((b * NOC + 2 * p + 1) * HN + h) * WN + w];
        float mk   = mask[((b * PN + p) * HN + h) * WN + w];

        float py = (float)(h + p / 3) + offy;   // padded space
        float px = (float)(w + p % 3) + offx;
        float fy0 = floorf(py);
        float fx0 = floorf(px);
        float wy1 = py - fy0, wx1 = px - fx0;
        float wy0 = 1.0f - wy1, wx0 = 1.0f - wx1;

        int iy0 = (int)fy0 - 1;   // x-space top-left corner
        int ix0 = (int)fx0 - 1;
        int iy1 = iy0 + 1, ix1 = ix0 + 1;
        bool vy0 = (iy0 >= 0) && (iy0 < HN);
        bool vy1 = (iy1 >= 0) && (iy1 < HN);
        bool vx0 = (ix0 >= 0) && (ix0 < WN);
        bool vx1 = (ix1 >= 0) && (ix1 < WN);

        float w00 = (vy0 && vx0) ? wy0 * wx0 * mk : 0.0f;
        float w01 = (vy0 && vx1) ? wy0 * wx1 * mk : 0.0f;
        float w10 = (vy1 && vx0) ? wy1 * wx0 * mk : 0.0f;
        float w11 = (vy1 && vx1) ? wy1 * wx1 * mk : 0.0f;

        int cy0 = min(max(iy0, 0), HN - 1), cy1 = min(max(iy1, 0), HN - 1);
        int cx0 = min(max(ix0, 0), WN - 1), cx1 = min(max(ix1, 0), WN - 1);
        int a00 = cy0 * WN + cx0, a01 = cy0 * WN + cx1;
        int a10 = cy1 * WN + cx0, a11 = cy1 * WN + cx1;

        const float* wp = wB + (p * CN + cbase) * ON + obase;
        const float* xc = xb;
#pragma unroll 4
        for (int c = 0; c < 16; c++, xc += HN * WN) {
            float v = w00 * xc[a00] + w01 * xc[a01] + w10 * xc[a10] + w11 * xc[a11];
            const float4* wc = (const float4*)(wp + c * ON);
#pragma unroll
            for (int o4 = 0; o4 < 8; o4++) {
                float4 wv = wc[o4];
                acc[o4 * 4 + 0] += wv.x * v;
                acc[o4 * 4 + 1] += wv.y * v;
                acc[o4 * 4 + 2] += wv.z * v;
                acc[o4 * 4 + 3] += wv.w * v;
            }
        }
    }

    // reduce the two cg groups
    if (cg == 1) {
        float* dst = red + wlane * 65 + obase;
#pragma unroll
        for (int o = 0; o < 32; o++) dst[o] = acc[o];
    }
    __syncthreads();
    if (cg == 0) {
        const float* src = red + wlane * 65 + obase;
        float* yp = ypart + (size_t)chalf * (BN * ON * HN * WN);
#pragma unroll
        for (int o = 0; o < 32; o++) {
            yp[((b * ON + obase + o) * HN + h) * WN + w] = acc[o] + src[o];
        }
    }
}

// y = ypart0 + ypart1 (written into ypart0), plus layernorm partials
__global__ __launch_bounds__(256) void reduce_kernel(float* __restrict__ yp0,
                                                     const float* __restrict__ yp1,
                                                     float2* __restrict__ partials) {
    int t = blockIdx.x * 256 + threadIdx.x;   // 2048*256 threads, 8 floats each
    float4* p0 = (float4*)yp0;
    const float4* p1 = (const float4*)yp1;
    float s1 = 0.0f, s2 = 0.0f;
#pragma unroll
    for (int i = 0; i < 2; i++) {
        int idx = t * 2 + i;
        float4 a = p0[idx];
        float4 bv = p1[idx];
        a.x += bv.x; a.y += bv.y; a.z += bv.z; a.w += bv.w;
        p0[idx] = a;
        s1 += a.x + a.y + a.z + a.w;
        s2 += a.x * a.x + a.y * a.y + a.z * a.z + a.w * a.w;
    }
    __shared__ float red1[256], red2[256];
    int tid = threadIdx.x;
    red1[tid] = s1;
    red2[tid] = s2;
    __syncthreads();
    for (int s = 128; s > 0; s >>= 1) {
        if (tid < s) { red1[tid] += red1[tid + s]; red2[tid] += red2[tid + s]; }
        __syncthreads();
    }
    if (tid == 0)
        partials[blockIdx.x] = make_float2(red1[0], red2[0]);
}

__global__ __launch_bounds__(256) void stats_kernel(const float2* __restrict__ partials,
                                                    int nblocks,
                                                    float* __restrict__ stats) {
    __shared__ double r1[256], r2[256];
    int tid = threadIdx.x;
    double s1 = 0.0, s2 = 0.0;
    for (int i = tid; i < nblocks; i += 256) {
        s1 += (double)partials[i].x;
        s2 += (double)partials[i].y;
    }
    r1[tid] = s1;
    r2[tid] = s2;
    __syncthreads();
    for (int s = 128; s > 0; s >>= 1) {
        if (tid < s) { r1[tid] += r1[tid + s]; r2[tid] += r2[tid + s]; }
        __syncthreads();
    }
    if (tid == 0) {
        double N = (double)BN * ON * HN * WN;
        double mu = r1[0] / N;
        double var = r2[0] / N - mu * mu;
        stats[0] = (float)mu;
        stats[1] = (float)(1.0 / sqrt(var + 1e-5));
    }
}

// normalize + prak + concat(x) + 3x3/2 maxpool
__global__ __launch_bounds__(256) void out_kernel(const float* __restrict__ yb,
                                                  const float* __restrict__ x,
                                                  const float* __restrict__ stats,
                                                  float* __restrict__ out) {
    int t = blockIdx.x * 256 + threadIdx.x;
    if (t >= BN * 128 * HO * WO) return;
    int ow = t % WO;
    int oh = (t / WO) % HO;
    int ch = (t / (WO * HO)) % 128;
    int b  = t / (WO * HO * 128);

    float mu = stats[0];
    float inv = stats[1];
    float m = -INFINITY;
    if (ch < 64) {
        const float* yc = yb + ((size_t)(b * ON + ch) * HN) * WN;
#pragma unroll
        for (int dy = 0; dy < 3; dy++) {
            const float* row = yc + (2 * oh + dy) * WN + 2 * ow;
#pragma unroll
            for (int dx = 0; dx < 3; dx++) {
                float v = prak_f((row[dx] - mu) * inv);
                m = fmaxf(m, v);
            }
        }
    } else {
        const float* xc = x + ((size_t)(b * CN + (ch - 64)) * HN) * WN;
#pragma unroll
        for (int dy = 0; dy < 3; dy++) {
            const float* row = xc + (2 * oh + dy) * WN + 2 * ow;
#pragma unroll
            for (int dx = 0; dx < 3; dx++) m = fmaxf(m, row[dx]);
        }
    }
    out[t] = m;
}

extern "C" void kernel_launch(void* const* d_in, const int* in_sizes, int n_in,
                              void* d_out, int out_size, void* d_ws, size_t ws_size,
                              hipStream_t stream) {
    const float* x    = (const float*)d_in[0];
    const float* offw = (const float*)d_in[1];
    const float* offb = (const float*)d_in[2];
    const float* wgt  = (const float*)d_in[3];
    const float* mask = (const float*)d_in[4];
    float* out = (float*)d_out;

    float* ws = (float*)d_ws;
    float* wA    = ws;                        // 10368
    float* wB    = wA + 10368;                // 36864
    float* offs  = wB + 36864;                // 1179648
    float* ypart = offs + 1179648;            // 2 x 4194304
    float2* partials = (float2*)(ypart + 2 * 4194304);  // 2048 float2
    float* stats = (float*)(partials + 2048);           // 2 floats

    prep_kernel<<<144, 256, 0, stream>>>(offw, wgt, wA, wB);
    offsets_kernel<<<1024, dim3(64, 4), 0, stream>>>(x, wA, offb, offs);
    deform_kernel<<<2048, dim3(64, 2, 2), 0, stream>>>(x, offs, mask, wB, ypart);
    reduce_kernel<<<2048, 256, 0, stream>>>(ypart, ypart + 4194304, partials);
    stats_kernel<<<1, 256, 0, stream>>>(partials, 2048, stats);
    out_kernel<<<7874, 256, 0, stream>>>(ypart, x, stats, out);
}

// Round 4
// 235.250 us; speedup vs baseline: 3.6647x; 3.6647x over previous
//
#include <hip/hip_runtime.h>
#include <math.h>

#define BN 4
#define CN 64
#define HN 64
#define WN 256
#define ON 64
#define NOC 18
#define PN 9
#define HO 31
#define WO 127

typedef __attribute__((ext_vector_type(8))) short bf16x8;
typedef __attribute__((ext_vector_type(4))) float f32x4;

__device__ __forceinline__ unsigned short f2bf(float f) {
    unsigned int u = __float_as_uint(f);
    unsigned int r = (u + 0x7fffu + ((u >> 16) & 1u)) >> 16;
    return (unsigned short)r;
}

__device__ __forceinline__ float trianglewave(float x) {
    const float PI_F = 3.14159274101257324f;   // float(np.pi)
    float n = floorf(x / PI_F + 0.5f);
    float m = fmodf(n, 2.0f);
    if (m < 0.0f) m += 2.0f;
    float sgn = 1.0f - 2.0f * m;
    return (x - PI_F * n) * sgn;
}

__device__ __forceinline__ float prak_f(float x) {
    const float PI_HALF = 1.57079637050628662f; // float(np.pi/2)
    return trianglewave(x) + trianglewave(x + PI_HALF);
}

// wA[c][k][oc] <- offset_w ; Wf = MFMA A-fragment-ordered bf16 copy of weight:
// Wf[((m*18+ks)*64+lane)*8+j] = bf16(W[o=m*16+(lane&15)][k=ks*32+(lane>>4)*8+j])
// with k = p*64+c  ->  weight[(o*64+c)*9+p]
__global__ void prep_kernel(const float* __restrict__ offw,
                            const float* __restrict__ wgt,
                            float* __restrict__ wA,
                            unsigned short* __restrict__ Wf) {
    int t = blockIdx.x * blockDim.x + threadIdx.x;
    if (t < CN * 9 * NOC) {
        int oc = t % NOC;
        int k  = (t / NOC) % 9;
        int c  = t / (NOC * 9);
        wA[t] = offw[(oc * CN + c) * 9 + k];
    }
    if (t < 4 * 18 * 64 * 8) {
        int j    = t & 7;
        int lane = (t >> 3) & 63;
        int rest = t >> 9;          // 0..71
        int ks   = rest % 18;
        int m    = rest / 18;
        int o = m * 16 + (lane & 15);
        int k = ks * 32 + (lane >> 4) * 8 + j;
        int c = k & 63;
        int p = k >> 6;
        Wf[t] = f2bf(wgt[(o * CN + c) * 9 + p]);
    }
}

// block (64 w-lanes, 4 c-groups); grid 1024 with XCD-chunked swizzle
__global__ __launch_bounds__(256) void offsets_kernel(const float* __restrict__ x,
                                                      const float* __restrict__ wA,
                                                      const float* __restrict__ offb,
                                                      float* __restrict__ offs) {
    __shared__ float red[4][64][19];
    int bid = blockIdx.x;
    int logical = ((bid & 7) << 7) + (bid >> 3);  // contiguous 128-chunk per XCD
    int b = logical >> 8;
    int h = (logical >> 2) & 63;
    int wblk = logical & 3;
    int wlane = threadIdx.x;
    int cg = threadIdx.y;
    int w = (wblk << 6) + wlane;

    float acc[NOC];
#pragma unroll
    for (int i = 0; i < NOC; i++) acc[i] = 0.0f;

    const float* xc = x + ((size_t)b * CN + cg * 16) * HN * WN;
    for (int c = 0; c < 16; c++, xc += HN * WN) {
        const float* wa = wA + ((cg * 16 + c) * 9) * NOC;
#pragma unroll
        for (int k = 0; k < 9; k++) {
            int iy = h + k / 3 - 1;
            int ix = w + k % 3 - 1;
            float xv = (iy >= 0 && iy < HN && ix >= 0 && ix < WN) ? xc[iy * WN + ix] : 0.0f;
#pragma unroll
            for (int oc = 0; oc < NOC; oc++) acc[oc] += xv * wa[k * NOC + oc];
        }
    }
#pragma unroll
    for (int oc = 0; oc < NOC; oc++) red[cg][wlane][oc] = acc[oc];
    __syncthreads();
    if (cg == 0) {
#pragma unroll
        for (int oc = 0; oc < NOC; oc++) {
            float t = red[0][wlane][oc] + red[1][wlane][oc] +
                      red[2][wlane][oc] + red[3][wlane][oc] + offb[oc];
            offs[((b * NOC + oc) * HN + h) * WN + w] = t;
        }
    }
}

// Fused im2col(LDS, bf16) + MFMA deformable conv.
// 512 threads = 8 waves per 64-pixel tile; grid 1024 XCD-swizzled.
// Phase 1: wave wv gathers channels [wv*8, wv*8+8) for all 9 taps into
//          V[pix][k=p*64+c] (bf16, 1168 B/pixel stride).
// Phase 2: wave wv computes output tiles (m=wv>>1, ntiles npair*2,+1) via
//          mfma_f32_16x16x32_bf16 over K=576.
__global__ __launch_bounds__(512, 4) void deform_mfma_kernel(
        const float* __restrict__ x,
        const float* __restrict__ offs,
        const float* __restrict__ mask,
        const unsigned short* __restrict__ Wf,
        float* __restrict__ y,
        float2* __restrict__ partials) {
    __shared__ __align__(16) unsigned short V[64 * 584];   // 74752 B
    __shared__ float red1[8], red2[8];

    int bid = blockIdx.x;
    int logical = ((bid & 7) << 7) + (bid >> 3);   // 8 XCDs x 128-chunk
    int b = logical >> 8;
    int h = (logical >> 2) & 63;
    int wblk = logical & 3;
    int lane = threadIdx.x & 63;
    int wv = threadIdx.x >> 6;          // 0..7
    int w = (wblk << 6) + lane;

    // ---------- Phase 1: gather/bilinear -> V ----------
    const float* xb = x + (size_t)b * CN * HN * WN;
    int cbase = wv * 8;
    for (int p = 0; p < PN; p++) {
        float offy = offs[((b * NOC + 2 * p) * HN + h) * WN + w];
        float offx = offs[((b * NOC + 2 * p + 1) * HN + h) * WN + w];
        float mk   = mask[((b * PN + p) * HN + h) * WN + w];

        float py = (float)(h + p / 3) + offy;   // padded space
        float px = (float)(w + p % 3) + offx;
        float fy0 = floorf(py);
        float fx0 = floorf(px);
        float wy1 = py - fy0, wx1 = px - fx0;
        float wy0 = 1.0f - wy1, wx0 = 1.0f - wx1;

        int iy0 = (int)fy0 - 1;   // x-space top-left
        int ix0 = (int)fx0 - 1;
        int iy1 = iy0 + 1, ix1 = ix0 + 1;
        bool vy0 = (iy0 >= 0) && (iy0 < HN);
        bool vy1 = (iy1 >= 0) && (iy1 < HN);
        bool vx0 = (ix0 >= 0) && (ix0 < WN);
        bool vx1 = (ix1 >= 0) && (ix1 < WN);

        float w00 = (vy0 && vx0) ? wy0 * wx0 * mk : 0.0f;
        float w01 = (vy0 && vx1) ? wy0 * wx1 * mk : 0.0f;
        float w10 = (vy1 && vx0) ? wy1 * wx0 * mk : 0.0f;
        float w11 = (vy1 && vx1) ? wy1 * wx1 * mk : 0.0f;

        int cy0 = min(max(iy0, 0), HN - 1), cy1 = min(max(iy1, 0), HN - 1);
        int cx0 = min(max(ix0, 0), WN - 1), cx1 = min(max(ix1, 0), WN - 1);
        int a00 = cy0 * WN + cx0, a01 = cy0 * WN + cx1;
        int a10 = cy1 * WN + cx0, a11 = cy1 * WN + cx1;

        const float* xc = xb + (size_t)cbase * HN * WN;
        char* vrow = (char*)V + lane * 1168 + (p * 64 + cbase) * 2;
#pragma unroll
        for (int cc = 0; cc < 8; cc += 2) {
            float v0 = w00 * xc[a00] + w01 * xc[a01] + w10 * xc[a10] + w11 * xc[a11];
            const float* xc1 = xc + HN * WN;
            float v1 = w00 * xc1[a00] + w01 * xc1[a01] + w10 * xc1[a10] + w11 * xc1[a11];
            xc += 2 * HN * WN;
            unsigned int pk = ((unsigned int)f2bf(v1) << 16) | (unsigned int)f2bf(v0);
            *(unsigned int*)(vrow + cc * 2) = pk;
        }
    }
    __syncthreads();

    // ---------- Phase 2: MFMA ----------
    int m = wv >> 1;            // M-tile 0..3
    int npair = wv & 1;         // N-tiles npair*2, npair*2+1
    f32x4 acc0 = {0.0f, 0.0f, 0.0f, 0.0f};
    f32x4 acc1 = {0.0f, 0.0f, 0.0f, 0.0f};
    const bf16x8* Wfv = (const bf16x8*)Wf;
    int pixc = npair * 32 + (lane & 15);
    int kq = lane >> 4;
#pragma unroll
    for (int ks = 0; ks < 18; ks++) {
        bf16x8 a  = Wfv[(m * 18 + ks) * 64 + lane];
        bf16x8 b0 = *(const bf16x8*)((char*)V + pixc * 1168 + ks * 64 + kq * 16);
        bf16x8 b1 = *(const bf16x8*)((char*)V + (pixc + 16) * 1168 + ks * 64 + kq * 16);
        acc0 = __builtin_amdgcn_mfma_f32_16x16x32_bf16(a, b0, acc0, 0, 0, 0);
        acc1 = __builtin_amdgcn_mfma_f32_16x16x32_bf16(a, b1, acc1, 0, 0, 0);
    }

    // C/D layout: col = lane&15 -> pixel; row = (lane>>4)*4 + reg -> o
    int orow = m * 16 + kq * 4;
    float s1 = 0.0f, s2 = 0.0f;
#pragma unroll
    for (int r = 0; r < 4; r++) {
        float v0 = acc0[r];
        float v1 = acc1[r];
        size_t base = (((size_t)(b * ON + orow + r) * HN) + h) * WN + (wblk << 6);
        y[base + pixc] = v0;
        y[base + pixc + 16] = v1;
        s1 += v0 + v1;
        s2 += v0 * v0 + v1 * v1;
    }
#pragma unroll
    for (int off = 32; off > 0; off >>= 1) {
        s1 += __shfl_down(s1, off);
        s2 += __shfl_down(s2, off);
    }
    if (lane == 0) { red1[wv] = s1; red2[wv] = s2; }
    __syncthreads();
    if (threadIdx.x == 0) {
        float t1 = 0.0f, t2 = 0.0f;
#pragma unroll
        for (int i = 0; i < 8; i++) { t1 += red1[i]; t2 += red2[i]; }
        partials[blockIdx.x] = make_float2(t1, t2);
    }
}

__global__ __launch_bounds__(256) void stats_kernel(const float2* __restrict__ partials,
                                                    int nblocks,
                                                    float* __restrict__ stats) {
    __shared__ double r1[256], r2[256];
    int tid = threadIdx.x;
    double s1 = 0.0, s2 = 0.0;
    for (int i = tid; i < nblocks; i += 256) {
        s1 += (double)partials[i].x;
        s2 += (double)partials[i].y;
    }
    r1[tid] = s1;
    r2[tid] = s2;
    __syncthreads();
    for (int s = 128; s > 0; s >>= 1) {
        if (tid < s) { r1[tid] += r1[tid + s]; r2[tid] += r2[tid + s]; }
        __syncthreads();
    }
    if (tid == 0) {
        double N = (double)BN * ON * HN * WN;
        double mu = r1[0] / N;
        double var = r2[0] / N - mu * mu;
        stats[0] = (float)mu;
        stats[1] = (float)(1.0 / sqrt(var + 1e-5));
    }
}

// normalize + prak + concat(x) + 3x3/2 maxpool
__global__ __launch_bounds__(256) void out_kernel(const float* __restrict__ yb,
                                                  const float* __restrict__ x,
                                                  const float* __restrict__ stats,
                                                  float* __restrict__ out) {
    int t = blockIdx.x * 256 + threadIdx.x;
    if (t >= BN * 128 * HO * WO) return;
    int ow = t % WO;
    int oh = (t / WO) % HO;
    int ch = (t / (WO * HO)) % 128;
    int b  = t / (WO * HO * 128);

    float mu = stats[0];
    float inv = stats[1];
    float m = -INFINITY;
    if (ch < 64) {
        const float* yc = yb + ((size_t)(b * ON + ch) * HN) * WN;
#pragma unroll
        for (int dy = 0; dy < 3; dy++) {
            const float* row = yc + (2 * oh + dy) * WN + 2 * ow;
#pragma unroll
            for (int dx = 0; dx < 3; dx++) {
                float v = prak_f((row[dx] - mu) * inv);
                m = fmaxf(m, v);
            }
        }
    } else {
        const float* xc = x + ((size_t)(b * CN + (ch - 64)) * HN) * WN;
#pragma unroll
        for (int dy = 0; dy < 3; dy++) {
            const float* row = xc + (2 * oh + dy) * WN + 2 * ow;
#pragma unroll
            for (int dx = 0; dx < 3; dx++) m = fmaxf(m, row[dx]);
        }
    }
    out[t] = m;
}

extern "C" void kernel_launch(void* const* d_in, const int* in_sizes, int n_in,
                              void* d_out, int out_size, void* d_ws, size_t ws_size,
                              hipStream_t stream) {
    const float* x    = (const float*)d_in[0];
    const float* offw = (const float*)d_in[1];
    const float* offb = (const float*)d_in[2];
    const float* wgt  = (const float*)d_in[3];
    const float* mask = (const float*)d_in[4];
    float* out = (float*)d_out;

    float* ws = (float*)d_ws;
    float* wA = ws;                                   // 10368 f
    unsigned short* Wf = (unsigned short*)(wA + 10368);  // 36864 bf16 = 18432 f
    float* offs = wA + 10368 + 18432;                 // 1179648 f
    float* y    = offs + 1179648;                     // 4194304 f
    float2* partials = (float2*)(y + 4194304);        // 1024 float2
    float* stats = (float*)(partials + 1024);         // 2 f

    prep_kernel<<<144, 256, 0, stream>>>(offw, wgt, wA, Wf);
    offsets_kernel<<<1024, dim3(64, 4), 0, stream>>>(x, wA, offb, offs);
    deform_mfma_kernel<<<1024, 512, 0, stream>>>(x, offs, mask, Wf, y, partials);
    stats_kernel<<<1, 256, 0, stream>>>(partials, 1024, stats);
    out_kernel<<<7874, 256, 0, stream>>>(y, x, stats, out);
}

// Round 6
// 176.958 us; speedup vs baseline: 4.8719x; 1.3294x over previous
//
#include <hip/hip_runtime.h>
#include <math.h>

#define BN 4
#define CN 64
#define HN 64
#define WN 256
#define ON 64
#define NOC 18
#define PN 9
#define HO 31
#define WO 127

typedef __attribute__((ext_vector_type(8))) short bf16x8;
typedef __attribute__((ext_vector_type(4))) float f32x4;

__device__ __forceinline__ unsigned short f2bf(float f) {
    unsigned int u = __float_as_uint(f);
    unsigned int r = (u + 0x7fffu + ((u >> 16) & 1u)) >> 16;
    return (unsigned short)r;
}

__device__ __forceinline__ float trianglewave(float x) {
    const float PI_F = 3.14159274101257324f;   // float(np.pi)
    float n = floorf(x / PI_F + 0.5f);
    float m = fmodf(n, 2.0f);
    if (m < 0.0f) m += 2.0f;
    float sgn = 1.0f - 2.0f * m;
    return (x - PI_F * n) * sgn;
}

__device__ __forceinline__ float prak_f(float x) {
    const float PI_HALF = 1.57079637050628662f; // float(np.pi/2)
    return trianglewave(x) + trianglewave(x + PI_HALF);
}

// wA[c][k][oc] <- offset_w ; Wf = MFMA A-fragment-ordered bf16 copy of weight
__global__ void prep_kernel(const float* __restrict__ offw,
                            const float* __restrict__ wgt,
                            float* __restrict__ wA,
                            unsigned short* __restrict__ Wf) {
    int t = blockIdx.x * blockDim.x + threadIdx.x;
    if (t < CN * 9 * NOC) {
        int oc = t % NOC;
        int k  = (t / NOC) % 9;
        int c  = t / (NOC * 9);
        wA[t] = offw[(oc * CN + c) * 9 + k];
    }
    if (t < 4 * 18 * 64 * 8) {
        int j    = t & 7;
        int lane = (t >> 3) & 63;
        int rest = t >> 9;          // 0..71
        int ks   = rest % 18;
        int m    = rest / 18;
        int o = m * 16 + (lane & 15);
        int k = ks * 32 + (lane >> 4) * 8 + j;
        int c = k & 63;
        int p = k >> 6;
        Wf[t] = f2bf(wgt[(o * CN + c) * 9 + p]);
    }
}

// x[b][c][h][w] -> x_t[b][h][w][c]
// thread: g = c-quad (0..15), w, h, b. Needs BN*HN*WN*16 = 1,048,576 threads.
__global__ __launch_bounds__(256) void transpose_kernel(const float* __restrict__ x,
                                                        float* __restrict__ xt) {
    int T = blockIdx.x * 256 + threadIdx.x;
    int g = T & 15;
    int w = (T >> 4) & 255;
    int h = (T >> 12) & 63;
    int b = T >> 18;          // 0..3 with grid 4096
    float4 v;
    int c0 = g * 4;
    v.x = x[((size_t)(b * CN + c0 + 0) * HN + h) * WN + w];
    v.y = x[((size_t)(b * CN + c0 + 1) * HN + h) * WN + w];
    v.z = x[((size_t)(b * CN + c0 + 2) * HN + h) * WN + w];
    v.w = x[((size_t)(b * CN + c0 + 3) * HN + h) * WN + w];
    *(float4*)(xt + (((size_t)(b * HN) + h) * WN + w) * 64 + c0) = v;
}

// offsets conv from x_t: block = 64 pixels, 512 threads.
// thread: pixel pl = t&63, cg = wave index (uniform) -> 8 channels.
__global__ __launch_bounds__(512) void offsets_kernel(const float* __restrict__ xt,
                                                      const float* __restrict__ wA,
                                                      const float* __restrict__ offb,
                                                      float* __restrict__ offs) {
    __shared__ float red[8][64][19];
    int bid = blockIdx.x;
    int logical = ((bid & 7) << 7) + (bid >> 3);  // XCD-chunked
    int b = logical >> 8;
    int h = (logical >> 2) & 63;
    int wblk = logical & 3;
    int pl = threadIdx.x & 63;
    int cg = __builtin_amdgcn_readfirstlane(threadIdx.x >> 6);  // wave-uniform
    int w = (wblk << 6) + pl;

    float acc[NOC];
#pragma unroll
    for (int i = 0; i < NOC; i++) acc[i] = 0.0f;

#pragma unroll
    for (int k = 0; k < 9; k++) {
        int iy = h + k / 3 - 1;
        int ix = w + k % 3 - 1;
        float4 v0 = {0.f, 0.f, 0.f, 0.f}, v1 = {0.f, 0.f, 0.f, 0.f};
        if (iy >= 0 && iy < HN && ix >= 0 && ix < WN) {
            const float4* src = (const float4*)(xt + (((size_t)(b * HN) + iy) * WN + ix) * 64 + cg * 8);
            v0 = src[0];
            v1 = src[1];
        }
        const float* wa = wA + (cg * 8) * 162 + k * NOC;   // [c][k][oc], c-stride 162
        float xv[8] = {v0.x, v0.y, v0.z, v0.w, v1.x, v1.y, v1.z, v1.w};
#pragma unroll
        for (int c = 0; c < 8; c++) {
            const float* war = wa + c * 162;
#pragma unroll
            for (int oc = 0; oc < NOC; oc++) acc[oc] += xv[c] * war[oc];
        }
    }
#pragma unroll
    for (int oc = 0; oc < NOC; oc++) red[cg][pl][oc] = acc[oc];
    __syncthreads();

    int wv = threadIdx.x >> 6;
    if (wv < 2) {
        int ocb = wv * 9;
#pragma unroll
        for (int j = 0; j < 9; j++) {
            int oc = ocb + j;
            float s = offb[oc];
#pragma unroll
            for (int g = 0; g < 8; g++) s += red[g][pl][oc];
            offs[((b * NOC + oc) * HN + h) * WN + w] = s;
        }
    }
}

// Fused im2col(LDS, bf16) + MFMA deformable conv, x_t-based gathers.
// Phase 1: thread (pl = t>>3, cg = t&7): 8 channels per corner via 2 float4.
// Phase 2: MFMA identical to R3.
__global__ __launch_bounds__(512) void deform_mfma_kernel(
        const float* __restrict__ xt,
        const float* __restrict__ offs,
        const float* __restrict__ mask,
        const unsigned short* __restrict__ Wf,
        float* __restrict__ y,
        float2* __restrict__ partials) {
    __shared__ __align__(16) unsigned short V[64 * 584];   // 74752 B
    __shared__ float red1[8], red2[8];

    int bid = blockIdx.x;
    int logical = ((bid & 7) << 7) + (bid >> 3);   // XCD-chunked
    int b = logical >> 8;
    int h = (logical >> 2) & 63;
    int wblk = logical & 3;

    // ---------- Phase 1 ----------
    {
        int pl = threadIdx.x >> 3;      // 0..63
        int cg = threadIdx.x & 7;       // 0..7
        int w = (wblk << 6) + pl;
        const float* xb = xt + ((size_t)(b * HN) * WN) * 64;

        for (int p = 0; p < PN; p++) {
            float offy = offs[((b * NOC + 2 * p) * HN + h) * WN + w];
            float offx = offs[((b * NOC + 2 * p + 1) * HN + h) * WN + w];
            float mk   = mask[((b * PN + p) * HN + h) * WN + w];

            float py = (float)(h + p / 3) + offy;   // padded space
            float px = (float)(w + p % 3) + offx;
            float fy0 = floorf(py);
            float fx0 = floorf(px);
            float wy1 = py - fy0, wx1 = px - fx0;
            float wy0 = 1.0f - wy1, wx0 = 1.0f - wx1;

            int iy0 = (int)fy0 - 1;   // x-space top-left
            int ix0 = (int)fx0 - 1;
            int iy1 = iy0 + 1, ix1 = ix0 + 1;
            bool vy0 = (iy0 >= 0) && (iy0 < HN);
            bool vy1 = (iy1 >= 0) && (iy1 < HN);
            bool vx0 = (ix0 >= 0) && (ix0 < WN);
            bool vx1 = (ix1 >= 0) && (ix1 < WN);

            float w00 = (vy0 && vx0) ? wy0 * wx0 * mk : 0.0f;
            float w01 = (vy0 && vx1) ? wy0 * wx1 * mk : 0.0f;
            float w10 = (vy1 && vx0) ? wy1 * wx0 * mk : 0.0f;
            float w11 = (vy1 && vx1) ? wy1 * wx1 * mk : 0.0f;

            int cy0 = min(max(iy0, 0), HN - 1), cy1 = min(max(iy1, 0), HN - 1);
            int cx0 = min(max(ix0, 0), WN - 1), cx1 = min(max(ix1, 0), WN - 1);

            const float4* p00 = (const float4*)(xb + ((size_t)cy0 * WN + cx0) * 64 + cg * 8);
            const float4* p01 = (const float4*)(xb + ((size_t)cy0 * WN + cx1) * 64 + cg * 8);
            const float4* p10 = (const float4*)(xb + ((size_t)cy1 * WN + cx0) * 64 + cg * 8);
            const float4* p11 = (const float4*)(xb + ((size_t)cy1 * WN + cx1) * 64 + cg * 8);

            float4 A0 = p00[0], A1 = p00[1];
            float4 B0 = p01[0], B1 = p01[1];
            float4 C0 = p10[0], C1 = p10[1];
            float4 D0 = p11[0], D1 = p11[1];

            float v0 = w00 * A0.x + w01 * B0.x + w10 * C0.x + w11 * D0.x;
            float v1 = w00 * A0.y + w01 * B0.y + w10 * C0.y + w11 * D0.y;
            float v2 = w00 * A0.z + w01 * B0.z + w10 * C0.z + w11 * D0.z;
            float v3 = w00 * A0.w + w01 * B0.w + w10 * C0.w + w11 * D0.w;
            float v4 = w00 * A1.x + w01 * B1.x + w10 * C1.x + w11 * D1.x;
            float v5 = w00 * A1.y + w01 * B1.y + w10 * C1.y + w11 * D1.y;
            float v6 = w00 * A1.z + w01 * B1.z + w10 * C1.z + w11 * D1.z;
            float v7 = w00 * A1.w + w01 * B1.w + w10 * C1.w + w11 * D1.w;

            uint4 pk;
            pk.x = ((unsigned int)f2bf(v1) << 16) | (unsigned int)f2bf(v0);
            pk.y = ((unsigned int)f2bf(v3) << 16) | (unsigned int)f2bf(v2);
            pk.z = ((unsigned int)f2bf(v5) << 16) | (unsigned int)f2bf(v4);
            pk.w = ((unsigned int)f2bf(v7) << 16) | (unsigned int)f2bf(v6);
            *(uint4*)((char*)V + pl * 1168 + p * 128 + cg * 16) = pk;
        }
    }
    __syncthreads();

    // ---------- Phase 2: MFMA ----------
    int lane = threadIdx.x & 63;
    int wv = threadIdx.x >> 6;          // 0..7
    int m = wv >> 1;            // M-tile 0..3
    int npair = wv & 1;         // N-tiles npair*2, npair*2+1
    f32x4 acc0 = {0.0f, 0.0f, 0.0f, 0.0f};
    f32x4 acc1 = {0.0f, 0.0f, 0.0f, 0.0f};
    const bf16x8* Wfv = (const bf16x8*)Wf;
    int pixc = npair * 32 + (lane & 15);
    int kq = lane >> 4;
#pragma unroll
    for (int ks = 0; ks < 18; ks++) {
        bf16x8 a  = Wfv[(m * 18 + ks) * 64 + lane];
        bf16x8 b0 = *(const bf16x8*)((char*)V + pixc * 1168 + ks * 64 + kq * 16);
        bf16x8 b1 = *(const bf16x8*)((char*)V + (pixc + 16) * 1168 + ks * 64 + kq * 16);
        acc0 = __builtin_amdgcn_mfma_f32_16x16x32_bf16(a, b0, acc0, 0, 0, 0);
        acc1 = __builtin_amdgcn_mfma_f32_16x16x32_bf16(a, b1, acc1, 0, 0, 0);
    }

    // C/D layout: col = lane&15 -> pixel; row = (lane>>4)*4 + reg -> o
    int orow = m * 16 + kq * 4;
    float s1 = 0.0f, s2 = 0.0f;
#pragma unroll
    for (int r = 0; r < 4; r++) {
        float v0 = acc0[r];
        float v1 = acc1[r];
        size_t base = (((size_t)(b * ON + orow + r) * HN) + h) * WN + (wblk << 6);
        y[base + pixc] = v0;
        y[base + pixc + 16] = v1;
        s1 += v0 + v1;
        s2 += v0 * v0 + v1 * v1;
    }
#pragma unroll
    for (int off = 32; off > 0; off >>= 1) {
        s1 += __shfl_down(s1, off);
        s2 += __shfl_down(s2, off);
    }
    if (lane == 0) { red1[wv] = s1; red2[wv] = s2; }
    __syncthreads();
    if (threadIdx.x == 0) {
        float t1 = 0.0f, t2 = 0.0f;
#pragma unroll
        for (int i = 0; i < 8; i++) { t1 += red1[i]; t2 += red2[i]; }
        partials[blockIdx.x] = make_float2(t1, t2);
    }
}

__global__ __launch_bounds__(256) void stats_kernel(const float2* __restrict__ partials,
                                                    int nblocks,
                                                    float* __restrict__ stats) {
    __shared__ double r1[256], r2[256];
    int tid = threadIdx.x;
    double s1 = 0.0, s2 = 0.0;
    for (int i = tid; i < nblocks; i += 256) {
        s1 += (double)partials[i].x;
        s2 += (double)partials[i].y;
    }
    r1[tid] = s1;
    r2[tid] = s2;
    __syncthreads();
    for (int s = 128; s > 0; s >>= 1) {
        if (tid < s) { r1[tid] += r1[tid + s]; r2[tid] += r2[tid + s]; }
        __syncthreads();
    }
    if (tid == 0) {
        double N = (double)BN * ON * HN * WN;
        double mu = r1[0] / N;
        double var = r2[0] / N - mu * mu;
        stats[0] = (float)mu;
        stats[1] = (float)(1.0 / sqrt(var + 1e-5));
    }
}

// normalize + prak + concat(x) + 3x3/2 maxpool
__global__ __launch_bounds__(256) void out_kernel(const float* __restrict__ yb,
                                                  const float* __restrict__ x,
                                                  const float* __restrict__ stats,
                                                  float* __restrict__ out) {
    int t = blockIdx.x * 256 + threadIdx.x;
    if (t >= BN * 128 * HO * WO) return;
    int ow = t % WO;
    int oh = (t / WO) % HO;
    int ch = (t / (WO * HO)) % 128;
    int b  = t / (WO * HO * 128);

    float mu = stats[0];
    float inv = stats[1];
    float m = -INFINITY;
    if (ch < 64) {
        const float* yc = yb + ((size_t)(b * ON + ch) * HN) * WN;
#pragma unroll
        for (int dy = 0; dy < 3; dy++) {
            const float* row = yc + (2 * oh + dy) * WN + 2 * ow;
#pragma unroll
            for (int dx = 0; dx < 3; dx++) {
                float v = prak_f((row[dx] - mu) * inv);
                m = fmaxf(m, v);
            }
        }
    } else {
        const float* xc = x + ((size_t)(b * CN + (ch - 64)) * HN) * WN;
#pragma unroll
        for (int dy = 0; dy < 3; dy++) {
            const float* row = xc + (2 * oh + dy) * WN + 2 * ow;
#pragma unroll
            for (int dx = 0; dx < 3; dx++) m = fmaxf(m, row[dx]);
        }
    }
    out[t] = m;
}

extern "C" void kernel_launch(void* const* d_in, const int* in_sizes, int n_in,
                              void* d_out, int out_size, void* d_ws, size_t ws_size,
                              hipStream_t stream) {
    const float* x    = (const float*)d_in[0];
    const float* offw = (const float*)d_in[1];
    const float* offb = (const float*)d_in[2];
    const float* wgt  = (const float*)d_in[3];
    const float* mask = (const float*)d_in[4];
    float* out = (float*)d_out;

    float* ws = (float*)d_ws;
    float* wA = ws;                                      // 10368 f
    unsigned short* Wf = (unsigned short*)(wA + 10368);  // 36864 bf16 = 18432 f
    float* offs = wA + 10368 + 18432;                    // 1179648 f
    float* y    = offs + 1179648;                        // 4194304 f
    float* xt   = y + 4194304;                           // 4194304 f
    float2* partials = (float2*)(xt + 4194304);          // 1024 float2
    float* stats = (float*)(partials + 1024);            // 2 f

    prep_kernel<<<144, 256, 0, stream>>>(offw, wgt, wA, Wf);
    transpose_kernel<<<4096, 256, 0, stream>>>(x, xt);
    offsets_kernel<<<1024, 512, 0, stream>>>(xt, wA, offb, offs);
    deform_mfma_kernel<<<1024, 512, 0, stream>>>(xt, offs, mask, Wf, y, partials);
    stats_kernel<<<1, 256, 0, stream>>>(partials, 1024, stats);
    out_kernel<<<7874, 256, 0, stream>>>(y, x, stats, out);
}

// Round 7
// 78.617 us; speedup vs baseline: 10.9661x; 2.2509x over previous
//
#include <hip/hip_runtime.h>
#include <math.h>

#define BN 4
#define CN 64
#define HN 64
#define WN 256
#define ON 64
#define NOC 18
#define PN 9
#define HO 31
#define WO 127

typedef __attribute__((ext_vector_type(8))) short bf16x8;
typedef __attribute__((ext_vector_type(4))) float f32x4;

__device__ __forceinline__ unsigned short f2bf(float f) {
    unsigned int u = __float_as_uint(f);
    unsigned int r = (u + 0x7fffu + ((u >> 16) & 1u)) >> 16;
    return (unsigned short)r;
}

__device__ __forceinline__ float trianglewave(float x) {
    const float PI_F = 3.14159274101257324f;   // float(np.pi)
    float n = floorf(x / PI_F + 0.5f);
    float m = fmodf(n, 2.0f);
    if (m < 0.0f) m += 2.0f;
    float sgn = 1.0f - 2.0f * m;
    return (x - PI_F * n) * sgn;
}

__device__ __forceinline__ float prak_f(float x) {
    const float PI_HALF = 1.57079637050628662f; // float(np.pi/2)
    return trianglewave(x) + trianglewave(x + PI_HALF);
}

// Wf  = MFMA A-fragment bf16 weight           (4 m-tiles x 18 ks x 64 lanes x 8)
// WoF = MFMA A-fragment bf16 offset weight    (2 m-tiles x 18 ks x 64 lanes x 8, rows>=18 zero)
__global__ void prep_kernel(const float* __restrict__ offw,
                            const float* __restrict__ wgt,
                            unsigned short* __restrict__ Wf,
                            unsigned short* __restrict__ WoF) {
    int t = blockIdx.x * blockDim.x + threadIdx.x;
    if (t < 4 * 18 * 64 * 8) {
        int j    = t & 7;
        int lane = (t >> 3) & 63;
        int rest = t >> 9;          // 0..71
        int ks   = rest % 18;
        int m    = rest / 18;
        int o = m * 16 + (lane & 15);
        int k = ks * 32 + (lane >> 4) * 8 + j;
        int c = k & 63;
        int p = k >> 6;
        Wf[t] = f2bf(wgt[(o * CN + c) * 9 + p]);
    }
    if (t < 2 * 18 * 64 * 8) {
        int j    = t & 7;
        int lane = (t >> 3) & 63;
        int rest = t >> 9;          // 0..35
        int ks   = rest % 18;
        int mo   = rest / 18;
        int o = mo * 16 + (lane & 15);
        int k = ks * 32 + (lane >> 4) * 8 + j;
        int c = k & 63;
        int p = k >> 6;
        WoF[t] = (o < NOC) ? f2bf(offw[(o * CN + c) * 9 + p]) : (unsigned short)0;
    }
}

// x[b][c][h][w] -> x_t[b][h][w][c];  needs BN*HN*WN*16 = 1,048,576 threads (grid 4096)
__global__ __launch_bounds__(256) void transpose_kernel(const float* __restrict__ x,
                                                        float* __restrict__ xt) {
    int T = blockIdx.x * 256 + threadIdx.x;
    int g = T & 15;
    int w = (T >> 4) & 255;
    int h = (T >> 12) & 63;
    int b = T >> 18;
    float4 v;
    int c0 = g * 4;
    v.x = x[((size_t)(b * CN + c0 + 0) * HN + h) * WN + w];
    v.y = x[((size_t)(b * CN + c0 + 1) * HN + h) * WN + w];
    v.z = x[((size_t)(b * CN + c0 + 2) * HN + h) * WN + w];
    v.w = x[((size_t)(b * CN + c0 + 3) * HN + h) * WN + w];
    *(float4*)(xt + (((size_t)(b * HN) + h) * WN + w) * 64 + c0) = v;
}

// Fully fused: im2col -> offsets MFMA -> deformable gather -> deform MFMA.
// 512 threads = 8 waves per 64-pixel tile; grid 1024 XCD-swizzled.
__global__ __launch_bounds__(512) void fused_kernel(
        const float* __restrict__ xt,
        const float* __restrict__ offb,
        const float* __restrict__ mask,
        const unsigned short* __restrict__ WoF,
        const unsigned short* __restrict__ Wf,
        float* __restrict__ y,
        float2* __restrict__ partials) {
    __shared__ __align__(16) unsigned short V[64 * 584];   // 74752 B (reused Vr->V)
    __shared__ float offs_lds[NOC * 64];                   // 4608 B
    __shared__ float red1[8], red2[8];

    int bid = blockIdx.x;
    int logical = ((bid & 7) << 7) + (bid >> 3);   // XCD-chunked
    int b = logical >> 8;
    int h = (logical >> 2) & 63;
    int wblk = logical & 3;
    int lane = threadIdx.x & 63;
    int wv = threadIdx.x >> 6;          // 0..7

    // ---------- Phase 0: regular im2col (bf16) ----------
    {
        int pl = threadIdx.x >> 3;      // 0..63
        int cg = threadIdx.x & 7;       // 0..7
        int w = (wblk << 6) + pl;
#pragma unroll
        for (int p = 0; p < PN; p++) {
            int iy = h + p / 3 - 1;
            int ix = w + p % 3 - 1;
            uint4 pk = {0u, 0u, 0u, 0u};
            if (iy >= 0 && iy < HN && ix >= 0 && ix < WN) {
                const float4* src = (const float4*)(xt + (((size_t)(b * HN) + iy) * WN + ix) * 64 + cg * 8);
                float4 v0 = src[0], v1 = src[1];
                pk.x = ((unsigned int)f2bf(v0.y) << 16) | (unsigned int)f2bf(v0.x);
                pk.y = ((unsigned int)f2bf(v0.w) << 16) | (unsigned int)f2bf(v0.z);
                pk.z = ((unsigned int)f2bf(v1.y) << 16) | (unsigned int)f2bf(v1.x);
                pk.w = ((unsigned int)f2bf(v1.w) << 16) | (unsigned int)f2bf(v1.z);
            }
            *(uint4*)((char*)V + pl * 1168 + p * 128 + cg * 16) = pk;
        }
    }
    __syncthreads();

    // ---------- Offsets MFMA: 18x576 @ 576x64 ----------
    {
        int mo = wv >> 2;       // 0..1
        int nt = wv & 3;        // 0..3
        f32x4 acc = {0.0f, 0.0f, 0.0f, 0.0f};
        const bf16x8* Wov = (const bf16x8*)WoF;
        int pixc = nt * 16 + (lane & 15);
        int kq = lane >> 4;
#pragma unroll
        for (int ks = 0; ks < 18; ks++) {
            bf16x8 a = Wov[(mo * 18 + ks) * 64 + lane];
            bf16x8 bfr = *(const bf16x8*)((char*)V + pixc * 1168 + ks * 64 + kq * 16);
            acc = __builtin_amdgcn_mfma_f32_16x16x32_bf16(a, bfr, acc, 0, 0, 0);
        }
        int ocb = mo * 16 + kq * 4;
#pragma unroll
        for (int r = 0; r < 4; r++) {
            int oc = ocb + r;
            if (oc < NOC) offs_lds[oc * 64 + pixc] = acc[r] + offb[oc];
        }
    }
    __syncthreads();

    // ---------- Phase 1: deformable gather (overwrites V) ----------
    {
        int pl = threadIdx.x >> 3;      // 0..63
        int cg = threadIdx.x & 7;       // 0..7
        int w = (wblk << 6) + pl;
        const float* xb = xt + ((size_t)(b * HN) * WN) * 64;

        for (int p = 0; p < PN; p++) {
            float offy = offs_lds[(2 * p) * 64 + pl];
            float offx = offs_lds[(2 * p + 1) * 64 + pl];
            float mk   = mask[((b * PN + p) * HN + h) * WN + w];

            float py = (float)(h + p / 3) + offy;   // padded space
            float px = (float)(w + p % 3) + offx;
            float fy0 = floorf(py);
            float fx0 = floorf(px);
            float wy1 = py - fy0, wx1 = px - fx0;
            float wy0 = 1.0f - wy1, wx0 = 1.0f - wx1;

            int iy0 = (int)fy0 - 1;   // x-space top-left
            int ix0 = (int)fx0 - 1;
            int iy1 = iy0 + 1, ix1 = ix0 + 1;
            bool vy0 = (iy0 >= 0) && (iy0 < HN);
            bool vy1 = (iy1 >= 0) && (iy1 < HN);
            bool vx0 = (ix0 >= 0) && (ix0 < WN);
            bool vx1 = (ix1 >= 0) && (ix1 < WN);

            float w00 = (vy0 && vx0) ? wy0 * wx0 * mk : 0.0f;
            float w01 = (vy0 && vx1) ? wy0 * wx1 * mk : 0.0f;
            float w10 = (vy1 && vx0) ? wy1 * wx0 * mk : 0.0f;
            float w11 = (vy1 && vx1) ? wy1 * wx1 * mk : 0.0f;

            int cy0 = min(max(iy0, 0), HN - 1), cy1 = min(max(iy1, 0), HN - 1);
            int cx0 = min(max(ix0, 0), WN - 1), cx1 = min(max(ix1, 0), WN - 1);

            const float4* p00 = (const float4*)(xb + ((size_t)cy0 * WN + cx0) * 64 + cg * 8);
            const float4* p01 = (const float4*)(xb + ((size_t)cy0 * WN + cx1) * 64 + cg * 8);
            const float4* p10 = (const float4*)(xb + ((size_t)cy1 * WN + cx0) * 64 + cg * 8);
            const float4* p11 = (const float4*)(xb + ((size_t)cy1 * WN + cx1) * 64 + cg * 8);

            float4 A0 = p00[0], A1 = p00[1];
            float4 B0 = p01[0], B1 = p01[1];
            float4 C0 = p10[0], C1 = p10[1];
            float4 D0 = p11[0], D1 = p11[1];

            float v0 = w00 * A0.x + w01 * B0.x + w10 * C0.x + w11 * D0.x;
            float v1 = w00 * A0.y + w01 * B0.y + w10 * C0.y + w11 * D0.y;
            float v2 = w00 * A0.z + w01 * B0.z + w10 * C0.z + w11 * D0.z;
            float v3 = w00 * A0.w + w01 * B0.w + w10 * C0.w + w11 * D0.w;
            float v4 = w00 * A1.x + w01 * B1.x + w10 * C1.x + w11 * D1.x;
            float v5 = w00 * A1.y + w01 * B1.y + w10 * C1.y + w11 * D1.y;
            float v6 = w00 * A1.z + w01 * B1.z + w10 * C1.z + w11 * D1.z;
            float v7 = w00 * A1.w + w01 * B1.w + w10 * C1.w + w11 * D1.w;

            uint4 pk;
            pk.x = ((unsigned int)f2bf(v1) << 16) | (unsigned int)f2bf(v0);
            pk.y = ((unsigned int)f2bf(v3) << 16) | (unsigned int)f2bf(v2);
            pk.z = ((unsigned int)f2bf(v5) << 16) | (unsigned int)f2bf(v4);
            pk.w = ((unsigned int)f2bf(v7) << 16) | (unsigned int)f2bf(v6);
            *(uint4*)((char*)V + pl * 1168 + p * 128 + cg * 16) = pk;
        }
    }
    __syncthreads();

    // ---------- Phase 2: deform MFMA ----------
    int m = wv >> 1;            // M-tile 0..3
    int npair = wv & 1;         // N-tiles npair*2, npair*2+1
    f32x4 acc0 = {0.0f, 0.0f, 0.0f, 0.0f};
    f32x4 acc1 = {0.0f, 0.0f, 0.0f, 0.0f};
    const bf16x8* Wfv = (const bf16x8*)Wf;
    int pixc = npair * 32 + (lane & 15);
    int kq = lane >> 4;
#pragma unroll
    for (int ks = 0; ks < 18; ks++) {
        bf16x8 a  = Wfv[(m * 18 + ks) * 64 + lane];
        bf16x8 b0 = *(const bf16x8*)((char*)V + pixc * 1168 + ks * 64 + kq * 16);
        bf16x8 b1 = *(const bf16x8*)((char*)V + (pixc + 16) * 1168 + ks * 64 + kq * 16);
        acc0 = __builtin_amdgcn_mfma_f32_16x16x32_bf16(a, b0, acc0, 0, 0, 0);
        acc1 = __builtin_amdgcn_mfma_f32_16x16x32_bf16(a, b1, acc1, 0, 0, 0);
    }

    // C/D layout: col = lane&15 -> pixel; row = (lane>>4)*4 + reg -> o
    int orow = m * 16 + kq * 4;
    float s1 = 0.0f, s2 = 0.0f;
#pragma unroll
    for (int r = 0; r < 4; r++) {
        float v0 = acc0[r];
        float v1 = acc1[r];
        size_t base = (((size_t)(b * ON + orow + r) * HN) + h) * WN + (wblk << 6);
        y[base + pixc] = v0;
        y[base + pixc + 16] = v1;
        s1 += v0 + v1;
        s2 += v0 * v0 + v1 * v1;
    }
#pragma unroll
    for (int off = 32; off > 0; off >>= 1) {
        s1 += __shfl_down(s1, off);
        s2 += __shfl_down(s2, off);
    }
    if (lane == 0) { red1[wv] = s1; red2[wv] = s2; }
    __syncthreads();
    if (threadIdx.x == 0) {
        float t1 = 0.0f, t2 = 0.0f;
#pragma unroll
        for (int i = 0; i < 8; i++) { t1 += red1[i]; t2 += red2[i]; }
        partials[blockIdx.x] = make_float2(t1, t2);
    }
}

__global__ __launch_bounds__(256) void stats_kernel(const float2* __restrict__ partials,
                                                    int nblocks,
                                                    float* __restrict__ stats) {
    __shared__ double r1[256], r2[256];
    int tid = threadIdx.x;
    double s1 = 0.0, s2 = 0.0;
    for (int i = tid; i < nblocks; i += 256) {
        s1 += (double)partials[i].x;
        s2 += (double)partials[i].y;
    }
    r1[tid] = s1;
    r2[tid] = s2;
    __syncthreads();
    for (int s = 128; s > 0; s >>= 1) {
        if (tid < s) { r1[tid] += r1[tid + s]; r2[tid] += r2[tid + s]; }
        __syncthreads();
    }
    if (tid == 0) {
        double N = (double)BN * ON * HN * WN;
        double mu = r1[0] / N;
        double var = r2[0] / N - mu * mu;
        stats[0] = (float)mu;
        stats[1] = (float)(1.0 / sqrt(var + 1e-5));
    }
}

// normalize + prak + concat(x) + 3x3/2 maxpool
__global__ __launch_bounds__(256) void out_kernel(const float* __restrict__ yb,
                                                  const float* __restrict__ x,
                                                  const float* __restrict__ stats,
                                                  float* __restrict__ out) {
    int t = blockIdx.x * 256 + threadIdx.x;
    if (t >= BN * 128 * HO * WO) return;
    int ow = t % WO;
    int oh = (t / WO) % HO;
    int ch = (t / (WO * HO)) % 128;
    int b  = t / (WO * HO * 128);

    float mu = stats[0];
    float inv = stats[1];
    float m = -INFINITY;
    if (ch < 64) {
        const float* yc = yb + ((size_t)(b * ON + ch) * HN) * WN;
#pragma unroll
        for (int dy = 0; dy < 3; dy++) {
            const float* row = yc + (2 * oh + dy) * WN + 2 * ow;
#pragma unroll
            for (int dx = 0; dx < 3; dx++) {
                float v = prak_f((row[dx] - mu) * inv);
                m = fmaxf(m, v);
            }
        }
    } else {
        const float* xc = x + ((size_t)(b * CN + (ch - 64)) * HN) * WN;
#pragma unroll
        for (int dy = 0; dy < 3; dy++) {
            const float* row = xc + (2 * oh + dy) * WN + 2 * ow;
#pragma unroll
            for (int dx = 0; dx < 3; dx++) m = fmaxf(m, row[dx]);
        }
    }
    out[t] = m;
}

extern "C" void kernel_launch(void* const* d_in, const int* in_sizes, int n_in,
                              void* d_out, int out_size, void* d_ws, size_t ws_size,
                              hipStream_t stream) {
    const float* x    = (const float*)d_in[0];
    const float* offw = (const float*)d_in[1];
    const float* offb = (const float*)d_in[2];
    const float* wgt  = (const float*)d_in[3];
    const float* mask = (const float*)d_in[4];
    float* out = (float*)d_out;

    float* ws = (float*)d_ws;
    unsigned short* Wf  = (unsigned short*)ws;            // 36864 bf16
    unsigned short* WoF = Wf + 36864;                     // 18432 bf16
    float* y  = (float*)(WoF + 18432 + 2048);             // align; 4194304 f
    float* xt = y + 4194304;                              // 4194304 f
    float2* partials = (float2*)(xt + 4194304);           // 1024 float2
    float* stats = (float*)(partials + 1024);             // 2 f

    prep_kernel<<<144, 256, 0, stream>>>(offw, wgt, Wf, WoF);
    transpose_kernel<<<4096, 256, 0, stream>>>(x, xt);
    fused_kernel<<<1024, 512, 0, stream>>>(xt, offb, mask, WoF, Wf, y, partials);
    stats_kernel<<<1, 256, 0, stream>>>(partials, 1024, stats);
    out_kernel<<<7874, 256, 0, stream>>>(y, x, stats, out);
}